// Round 2
// baseline (279.419 us; speedup 1.0000x reference)
//
#include <hip/hip_runtime.h>

typedef __bf16 bf16;
typedef __bf16 bf16x4 __attribute__((ext_vector_type(4)));
typedef __bf16 bf16x8 __attribute__((ext_vector_type(8)));
typedef float f32x4 __attribute__((ext_vector_type(4)));

#define DIMD 1024
#define NHEAD 16
#define HDIM 64
#define BATCH 2
#define SEQ 2048
#define MTOT (BATCH*SEQ)   // 4096

// ---- memory plan (ws_size may be small; total ws use = 16 MB exactly) ----
// d_out (16MB fp32 capacity, final result written only by proj GEMM):
//   [0,8MB)  Qb bf16 [32][2048][64]  (pre-scaled by 1/8)
//   [8,16MB) Kb bf16 [32][2048][64]
// d_ws:
//   [0,8MB)  Vt bf16 [32][64][2048]   -- dead after attn, then wprojb at [0,2MB)
//   [8,14MB) wqkvb bf16 [3072][1024]  -- dead after QKV GEMM
//   [8,16MB) Ob bf16 [4096][1024]     -- written by attn (wqkvb dead by then)
#define OFF_VT    (0ull)
#define OFF_WQKV  (8ull<<20)
#define OFF_OB    (8ull<<20)
#define OFF_WPROJ (0ull)

__device__ __forceinline__ void g2l16(const void* g, void* l) {
  __builtin_amdgcn_global_load_lds(
      (const __attribute__((address_space(1))) void*)g,
      (__attribute__((address_space(3))) void*)l,
      16, 0, 0);
}

// ---------------- fp32 -> bf16 conversion ----------------
__global__ __launch_bounds__(256) void cvt_kernel(const float* __restrict__ in,
                                                  bf16* __restrict__ out, int n4) {
  int i = blockIdx.x * blockDim.x + threadIdx.x;
  if (i < n4) {
    float4 v = ((const float4*)in)[i];
    bf16x4 o = { (bf16)v.x, (bf16)v.y, (bf16)v.z, (bf16)v.w };
    ((bf16x4*)out)[i] = o;
  }
}

// ---------------- QKV GEMM: C[m][n] = sum_k x[m][k]*Wt[n][k] + b ----------------
// A (x) is fp32: fused convert during LDS staging (float4 load + cvt + ds_write).
// B (w_qkv bf16) staged via global_load_lds width=16.
// 128x128 tile, BK=32, 256 threads (2x2 waves, 4x4 frags/wave).
// Epilogue scatters Q (scaled 1/8), K, Vt into bf16 attention layouts.
__global__ __launch_bounds__(256, 2) void gemm_qkv(
    const float* __restrict__ x, const bf16* __restrict__ Wt,
    const float* __restrict__ bias,
    bf16* __restrict__ Qb, bf16* __restrict__ Kb, bf16* __restrict__ Vt)
{
  __shared__ bf16 lA[128 * 32];
  __shared__ bf16 lB[128 * 32];
  const int tid = threadIdx.x;
  const int wave = tid >> 6, lane = tid & 63;
  const int l15 = lane & 15, quad = lane >> 4;
  const int wm = wave >> 1, wn = wave & 1;
  const int tm = blockIdx.y * 128, tn = blockIdx.x * 128;

  f32x4 acc[4][4] = {};

  const int arowA = tid >> 1;            // 0..127
  const int acolA = (tid & 1) * 16;      // 0 or 16
  const int brow = tid >> 2;             // 0..63
  const int bchunk = (tid & 3) * 8;

  for (int kb = 0; kb < DIMD; kb += 32) {
    const float* gx = &x[(size_t)(tm + arowA) * DIMD + kb + acolA];
    float4 v0 = ((const float4*)gx)[0];
    float4 v1 = ((const float4*)gx)[1];
    float4 v2 = ((const float4*)gx)[2];
    float4 v3 = ((const float4*)gx)[3];
    __syncthreads();
    const bf16* gB = &Wt[(size_t)(tn + brow) * DIMD + kb + bchunk];
    g2l16(gB,                    &lB[wave * 512]);
    g2l16(gB + (size_t)64 * DIMD, &lB[2048 + wave * 512]);
    bf16x8 a0 = { (bf16)v0.x, (bf16)v0.y, (bf16)v0.z, (bf16)v0.w,
                  (bf16)v1.x, (bf16)v1.y, (bf16)v1.z, (bf16)v1.w };
    bf16x8 a1 = { (bf16)v2.x, (bf16)v2.y, (bf16)v2.z, (bf16)v2.w,
                  (bf16)v3.x, (bf16)v3.y, (bf16)v3.z, (bf16)v3.w };
    *(bf16x8*)&lA[arowA * 32 + acolA]     = a0;
    *(bf16x8*)&lA[arowA * 32 + acolA + 8] = a1;
    __syncthreads();

    bf16x8 af[4], bfr[4];
#pragma unroll
    for (int i = 0; i < 4; i++)
      af[i] = *(const bf16x8*)&lA[(wm * 64 + i * 16 + l15) * 32 + quad * 8];
#pragma unroll
    for (int i = 0; i < 4; i++)
      bfr[i] = *(const bf16x8*)&lB[(wn * 64 + i * 16 + l15) * 32 + quad * 8];
#pragma unroll
    for (int i = 0; i < 4; i++)
#pragma unroll
      for (int j = 0; j < 4; j++)
        acc[i][j] = __builtin_amdgcn_mfma_f32_16x16x32_bf16(af[i], bfr[j], acc[i][j], 0, 0, 0);
  }

  // epilogue: C row = tm + wm*64 + i*16 + quad*4 + r ; col = tn + wn*64 + j*16 + l15
  const int sel = tn >> 10;  // 0=Q 1=K 2=V (uniform: 1024 % 128 == 0)
#pragma unroll
  for (int j = 0; j < 4; j++) {
    const int n = tn + wn * 64 + j * 16 + l15;
    const float bv = bias[n];
    const int d = n & 1023, h = d >> 6, hd = d & 63;
#pragma unroll
    for (int i = 0; i < 4; i++) {
      const int mbase = tm + wm * 64 + i * 16 + quad * 4;
#pragma unroll
      for (int r = 0; r < 4; r++) {
        const int mm = mbase + r;
        const int b = mm >> 11, s = mm & 2047;
        const int bh = b * NHEAD + h;
        float v = acc[i][j][r] + bv;
        if (sel == 0)      Qb[((size_t)bh * SEQ + s) * HDIM + hd] = (bf16)(v * 0.125f);
        else if (sel == 1) Kb[((size_t)bh * SEQ + s) * HDIM + hd] = (bf16)v;
        else               Vt[((size_t)bh * HDIM + hd) * SEQ + s] = (bf16)v;
      }
    }
  }
}

// ---------------- proj GEMM: out[m][n] = sum_k Ob[m][k]*Wp[n][k] + b ----------------
__global__ __launch_bounds__(256, 2) void gemm_proj(
    const bf16* __restrict__ A, const bf16* __restrict__ Bt,
    const float* __restrict__ bias, float* __restrict__ out)
{
  __shared__ bf16 lA[128 * 32];
  __shared__ bf16 lB[128 * 32];
  const int tid = threadIdx.x;
  const int wave = tid >> 6, lane = tid & 63;
  const int l15 = lane & 15, quad = lane >> 4;
  const int wm = wave >> 1, wn = wave & 1;
  const int tm = blockIdx.y * 128, tn = blockIdx.x * 128;

  f32x4 acc[4][4] = {};
  const int arow = tid >> 2;
  const int achunk = (tid & 3) * 8;

  for (int kb = 0; kb < DIMD; kb += 32) {
    __syncthreads();
    const bf16* gA = &A[(size_t)(tm + arow) * DIMD + kb + achunk];
    const bf16* gB = &Bt[(size_t)(tn + arow) * DIMD + kb + achunk];
    g2l16(gA,                     &lA[wave * 512]);
    g2l16(gA + (size_t)64 * DIMD, &lA[2048 + wave * 512]);
    g2l16(gB,                     &lB[wave * 512]);
    g2l16(gB + (size_t)64 * DIMD, &lB[2048 + wave * 512]);
    __syncthreads();

    bf16x8 af[4], bfr[4];
#pragma unroll
    for (int i = 0; i < 4; i++)
      af[i] = *(const bf16x8*)&lA[(wm * 64 + i * 16 + l15) * 32 + quad * 8];
#pragma unroll
    for (int i = 0; i < 4; i++)
      bfr[i] = *(const bf16x8*)&lB[(wn * 64 + i * 16 + l15) * 32 + quad * 8];
#pragma unroll
    for (int i = 0; i < 4; i++)
#pragma unroll
      for (int j = 0; j < 4; j++)
        acc[i][j] = __builtin_amdgcn_mfma_f32_16x16x32_bf16(af[i], bfr[j], acc[i][j], 0, 0, 0);
  }

#pragma unroll
  for (int j = 0; j < 4; j++) {
    const int n = tn + wn * 64 + j * 16 + l15;
    const float bv = bias[n];
#pragma unroll
    for (int i = 0; i < 4; i++) {
      const int mbase = tm + wm * 64 + i * 16 + quad * 4;
#pragma unroll
      for (int r = 0; r < 4; r++)
        out[(size_t)(mbase + r) * DIMD + n] = acc[i][j][r] + bv;
    }
  }
}

// ---------------- flash attention ----------------
// grid: 1024 blocks = 32 bh * 32 q-tiles(64 rows). 4 waves x 16 q-rows.
// K-tiles of 64 keys. LDS stride 72 (=64+8) kills stride-64 bank conflicts.
#define LSTR 72
__global__ __launch_bounds__(256, 2) void attn_kernel(
    const bf16* __restrict__ Qb, const bf16* __restrict__ Kb,
    const bf16* __restrict__ Vt, bf16* __restrict__ Ob)
{
  __shared__ bf16 lK[64 * LSTR];
  __shared__ bf16 lV[64 * LSTR];
  __shared__ bf16 lP[4][16 * LSTR];

  const int tid = threadIdx.x;
  const int wave = tid >> 6, lane = tid & 63;
  const int l15 = lane & 15, quad = lane >> 4;
  const int qt = blockIdx.x & 31;
  const int bh = blockIdx.x >> 5;

  // Q fragments (A-operand: row=l15, k=quad*8+j), held in regs for whole block
  const int qrow = qt * 64 + wave * 16 + l15;
  const bf16* qptr = Qb + ((size_t)bh * SEQ + qrow) * HDIM + quad * 8;
  bf16x8 qf0 = *(const bf16x8*)qptr;
  bf16x8 qf1 = *(const bf16x8*)(qptr + 32);

  f32x4 oacc[4] = {};
  float mrow[4], lrow[4];
#pragma unroll
  for (int r = 0; r < 4; r++) { mrow[r] = -1e30f; lrow[r] = 0.f; }

  for (int kt = 0; kt < SEQ / 64; kt++) {
    __syncthreads();
#pragma unroll
    for (int it = 0; it < 2; it++) {
      const int idx = tid + it * 256;
      const int row = idx >> 3, ch = (idx & 7) * 8;
      *(uint4*)&lK[row * LSTR + ch] =
          *(const uint4*)&Kb[((size_t)bh * SEQ + kt * 64 + row) * HDIM + ch];
      *(uint4*)&lV[row * LSTR + ch] =
          *(const uint4*)&Vt[((size_t)bh * HDIM + row) * SEQ + kt * 64 + ch];
    }
    __syncthreads();

    // S = Q K^T  (rows = q (quad*4+r), cols = key (fn*16+l15))
    f32x4 sacc[4];
#pragma unroll
    for (int fn = 0; fn < 4; fn++) {
      f32x4 a = {};
      bf16x8 kf0 = *(const bf16x8*)&lK[(fn * 16 + l15) * LSTR + quad * 8];
      bf16x8 kf1 = *(const bf16x8*)&lK[(fn * 16 + l15) * LSTR + 32 + quad * 8];
      a = __builtin_amdgcn_mfma_f32_16x16x32_bf16(qf0, kf0, a, 0, 0, 0);
      a = __builtin_amdgcn_mfma_f32_16x16x32_bf16(qf1, kf1, a, 0, 0, 0);
      sacc[fn] = a;
    }

    // online softmax (rowwise over 16 lanes sharing a quad)
    float newm[4];
#pragma unroll
    for (int r = 0; r < 4; r++) {
      float mx = fmaxf(fmaxf(sacc[0][r], sacc[1][r]), fmaxf(sacc[2][r], sacc[3][r]));
#pragma unroll
      for (int off = 1; off < 16; off <<= 1) mx = fmaxf(mx, __shfl_xor(mx, off, 64));
      const float nm = fmaxf(mrow[r], mx);
      const float alpha = __expf(mrow[r] - nm);
      newm[r] = nm;
      mrow[r] = nm;
      lrow[r] *= alpha;
#pragma unroll
      for (int fd = 0; fd < 4; fd++) oacc[fd][r] *= alpha;
    }
#pragma unroll
    for (int r = 0; r < 4; r++) {
      float rs = 0.f;
#pragma unroll
      for (int fn = 0; fn < 4; fn++) {
        const float p = __expf(sacc[fn][r] - newm[r]);
        sacc[fn][r] = p;
        rs += p;
      }
#pragma unroll
      for (int off = 1; off < 16; off <<= 1) rs += __shfl_xor(rs, off, 64);
      lrow[r] += rs;
    }

    // P: C-layout -> A-layout via wave-private LDS (no barrier needed)
#pragma unroll
    for (int fn = 0; fn < 4; fn++)
#pragma unroll
      for (int r = 0; r < 4; r++)
        lP[wave][(quad * 4 + r) * LSTR + fn * 16 + l15] = (bf16)sacc[fn][r];
    bf16x8 pf0 = *(const bf16x8*)&lP[wave][l15 * LSTR + quad * 8];
    bf16x8 pf1 = *(const bf16x8*)&lP[wave][l15 * LSTR + 32 + quad * 8];

    // O += P V   (B-operand from Vt rows: row=d (fd*16+l15), k=key contiguous)
#pragma unroll
    for (int fd = 0; fd < 4; fd++) {
      bf16x8 vf0 = *(const bf16x8*)&lV[(fd * 16 + l15) * LSTR + quad * 8];
      bf16x8 vf1 = *(const bf16x8*)&lV[(fd * 16 + l15) * LSTR + 32 + quad * 8];
      oacc[fd] = __builtin_amdgcn_mfma_f32_16x16x32_bf16(pf0, vf0, oacc[fd], 0, 0, 0);
      oacc[fd] = __builtin_amdgcn_mfma_f32_16x16x32_bf16(pf1, vf1, oacc[fd], 0, 0, 0);
    }
  }

  // epilogue: O[b][s][h*64+hd] bf16 (feeds proj GEMM as A)
  const int b = bh >> 4, h = bh & 15;
#pragma unroll
  for (int r = 0; r < 4; r++) {
    const float inv = 1.f / lrow[r];
    const int s = qt * 64 + wave * 16 + quad * 4 + r;
#pragma unroll
    for (int fd = 0; fd < 4; fd++) {
      const int hd = fd * 16 + l15;
      Ob[((size_t)b * SEQ + s) * DIMD + h * HDIM + hd] = (bf16)(oacc[fd][r] * inv);
    }
  }
}

extern "C" void kernel_launch(void* const* d_in, const int* in_sizes, int n_in,
                              void* d_out, int out_size, void* d_ws, size_t ws_size,
                              hipStream_t stream) {
  const float* x      = (const float*)d_in[0];
  const float* b_qkv  = (const float*)d_in[2];
  const float* w_qkv  = (const float*)d_in[1];
  const float* w_proj = (const float*)d_in[3];
  const float* b_proj = (const float*)d_in[4];
  float* out = (float*)d_out;
  char* ws = (char*)d_ws;

  // scratch inside d_out (dead until proj GEMM writes the final result)
  bf16* Qb = (bf16*)d_out;                       // [0,8MB)
  bf16* Kb = (bf16*)d_out + (size_t)MTOT * DIMD; // [8,16MB)
  // scratch inside ws (16MB total)
  bf16* Vt     = (bf16*)(ws + OFF_VT);
  bf16* wqkvb  = (bf16*)(ws + OFF_WQKV);
  bf16* Ob     = (bf16*)(ws + OFF_OB);     // overlays wqkvb (dead after QKV GEMM)
  bf16* wprojb = (bf16*)(ws + OFF_WPROJ);  // overlays Vt (dead after attn)

  cvt_kernel<<<(3 * DIMD * DIMD / 4) / 256, 256, 0, stream>>>(w_qkv, wqkvb, 3 * DIMD * DIMD / 4);
  gemm_qkv<<<dim3(24, 32), 256, 0, stream>>>(x, wqkvb, b_qkv, Qb, Kb, Vt);
  attn_kernel<<<BATCH * NHEAD * (SEQ / 64), 256, 0, stream>>>(Qb, Kb, Vt, Ob);
  cvt_kernel<<<(DIMD * DIMD / 4) / 256, 256, 0, stream>>>(w_proj, wprojb, DIMD * DIMD / 4);
  gemm_proj<<<dim3(8, 32), 256, 0, stream>>>(Ob, wprojb, b_proj, out);
}

// Round 3
// 239.206 us; speedup vs baseline: 1.1681x; 1.1681x over previous
//
#include <hip/hip_runtime.h>

typedef __bf16 bf16;
typedef __bf16 bf16x4 __attribute__((ext_vector_type(4)));
typedef __bf16 bf16x8 __attribute__((ext_vector_type(8)));
typedef float f32x4 __attribute__((ext_vector_type(4)));

#define DIMD 1024
#define NHEAD 16
#define HDIM 64
#define BATCH 2
#define SEQ 2048
#define MTOT (BATCH*SEQ)   // 4096

// ---- memory plan (total ws use = 16 MB) ----
// d_out: [0,8MB) Qb bf16 [32][2048][64] (pre-scaled 1/8); [8,16MB) Kb
// d_ws:  [0,8MB) Vt bf16 [32][64][2048] -> dead after attn, wprojb at [0,2MB)
//        [8,14MB) wqkvb -> dead after QKV GEMM; [8,16MB) Ob bf16 [4096][1024]
#define OFF_VT    (0ull)
#define OFF_WQKV  (8ull<<20)
#define OFF_OB    (8ull<<20)
#define OFF_WPROJ (0ull)

__device__ __forceinline__ void g2l16(const void* g, void* l) {
  __builtin_amdgcn_global_load_lds(
      (const __attribute__((address_space(1))) void*)g,
      (__attribute__((address_space(3))) void*)l,
      16, 0, 0);
}

// ---------------- fp32 -> bf16 conversion ----------------
__global__ __launch_bounds__(256) void cvt_kernel(const float* __restrict__ in,
                                                  bf16* __restrict__ out, int n4) {
  int i = blockIdx.x * blockDim.x + threadIdx.x;
  if (i < n4) {
    float4 v = ((const float4*)in)[i];
    bf16x4 o = { (bf16)v.x, (bf16)v.y, (bf16)v.z, (bf16)v.w };
    ((bf16x4*)out)[i] = o;
  }
}

// ---------------- QKV GEMM: C[m][n] = sum_k x[m][k]*Wt[n][k] + b ----------------
__global__ __launch_bounds__(256, 2) void gemm_qkv(
    const float* __restrict__ x, const bf16* __restrict__ Wt,
    const float* __restrict__ bias,
    bf16* __restrict__ Qb, bf16* __restrict__ Kb, bf16* __restrict__ Vt)
{
  __shared__ bf16 lA[128 * 32];
  __shared__ bf16 lB[128 * 32];
  const int tid = threadIdx.x;
  const int wave = tid >> 6, lane = tid & 63;
  const int l15 = lane & 15, quad = lane >> 4;
  const int wm = wave >> 1, wn = wave & 1;
  const int tm = blockIdx.y * 128, tn = blockIdx.x * 128;

  f32x4 acc[4][4] = {};

  const int arowA = tid >> 1;            // 0..127
  const int acolA = (tid & 1) * 16;      // 0 or 16
  const int brow = tid >> 2;             // 0..63
  const int bchunk = (tid & 3) * 8;

  for (int kb = 0; kb < DIMD; kb += 32) {
    const float* gx = &x[(size_t)(tm + arowA) * DIMD + kb + acolA];
    float4 v0 = ((const float4*)gx)[0];
    float4 v1 = ((const float4*)gx)[1];
    float4 v2 = ((const float4*)gx)[2];
    float4 v3 = ((const float4*)gx)[3];
    __syncthreads();
    const bf16* gB = &Wt[(size_t)(tn + brow) * DIMD + kb + bchunk];
    g2l16(gB,                     &lB[wave * 512]);
    g2l16(gB + (size_t)64 * DIMD, &lB[2048 + wave * 512]);
    bf16x8 a0 = { (bf16)v0.x, (bf16)v0.y, (bf16)v0.z, (bf16)v0.w,
                  (bf16)v1.x, (bf16)v1.y, (bf16)v1.z, (bf16)v1.w };
    bf16x8 a1 = { (bf16)v2.x, (bf16)v2.y, (bf16)v2.z, (bf16)v2.w,
                  (bf16)v3.x, (bf16)v3.y, (bf16)v3.z, (bf16)v3.w };
    *(bf16x8*)&lA[arowA * 32 + acolA]     = a0;
    *(bf16x8*)&lA[arowA * 32 + acolA + 8] = a1;
    __syncthreads();

    bf16x8 af[4], bfr[4];
#pragma unroll
    for (int i = 0; i < 4; i++)
      af[i] = *(const bf16x8*)&lA[(wm * 64 + i * 16 + l15) * 32 + quad * 8];
#pragma unroll
    for (int i = 0; i < 4; i++)
      bfr[i] = *(const bf16x8*)&lB[(wn * 64 + i * 16 + l15) * 32 + quad * 8];
#pragma unroll
    for (int i = 0; i < 4; i++)
#pragma unroll
      for (int j = 0; j < 4; j++)
        acc[i][j] = __builtin_amdgcn_mfma_f32_16x16x32_bf16(af[i], bfr[j], acc[i][j], 0, 0, 0);
  }

  const int sel = tn >> 10;  // 0=Q 1=K 2=V
#pragma unroll
  for (int j = 0; j < 4; j++) {
    const int n = tn + wn * 64 + j * 16 + l15;
    const float bv = bias[n];
    const int d = n & 1023, h = d >> 6, hd = d & 63;
#pragma unroll
    for (int i = 0; i < 4; i++) {
      const int mbase = tm + wm * 64 + i * 16 + quad * 4;
#pragma unroll
      for (int r = 0; r < 4; r++) {
        const int mm = mbase + r;
        const int b = mm >> 11, s = mm & 2047;
        const int bh = b * NHEAD + h;
        float v = acc[i][j][r] + bv;
        if (sel == 0)      Qb[((size_t)bh * SEQ + s) * HDIM + hd] = (bf16)(v * 0.125f);
        else if (sel == 1) Kb[((size_t)bh * SEQ + s) * HDIM + hd] = (bf16)v;
        else               Vt[((size_t)bh * HDIM + hd) * SEQ + s] = (bf16)v;
      }
    }
  }
}

// ---------------- proj GEMM: 64x128 tile (512 blocks = 2/CU) ----------------
__global__ __launch_bounds__(256, 2) void gemm_proj(
    const bf16* __restrict__ A, const bf16* __restrict__ Bt,
    const float* __restrict__ bias, float* __restrict__ out)
{
  __shared__ bf16 lA[64 * 32];
  __shared__ bf16 lB[128 * 32];
  const int tid = threadIdx.x;
  const int wave = tid >> 6, lane = tid & 63;
  const int l15 = lane & 15, quad = lane >> 4;
  const int tm = blockIdx.y * 64, tn = blockIdx.x * 128;

  f32x4 acc[4][2] = {};
  const int row = tid >> 2;          // 0..63
  const int ch = (tid & 3) * 8;

  for (int kb = 0; kb < DIMD; kb += 32) {
    __syncthreads();
    g2l16(&A[(size_t)(tm + row) * DIMD + kb + ch],        &lA[wave * 512]);
    g2l16(&Bt[(size_t)(tn + row) * DIMD + kb + ch],       &lB[wave * 512]);
    g2l16(&Bt[(size_t)(tn + 64 + row) * DIMD + kb + ch],  &lB[2048 + wave * 512]);
    __syncthreads();

    bf16x8 af[4], bfr[2];
#pragma unroll
    for (int i = 0; i < 4; i++)
      af[i] = *(const bf16x8*)&lA[(i * 16 + l15) * 32 + quad * 8];
#pragma unroll
    for (int j = 0; j < 2; j++)
      bfr[j] = *(const bf16x8*)&lB[(wave * 32 + j * 16 + l15) * 32 + quad * 8];
#pragma unroll
    for (int i = 0; i < 4; i++)
#pragma unroll
      for (int j = 0; j < 2; j++)
        acc[i][j] = __builtin_amdgcn_mfma_f32_16x16x32_bf16(af[i], bfr[j], acc[i][j], 0, 0, 0);
  }

#pragma unroll
  for (int j = 0; j < 2; j++) {
    const int n = tn + wave * 32 + j * 16 + l15;
    const float bv = bias[n];
#pragma unroll
    for (int i = 0; i < 4; i++) {
      const int mbase = tm + i * 16 + quad * 4;
#pragma unroll
      for (int r = 0; r < 4; r++)
        out[(size_t)(mbase + r) * DIMD + n] = acc[i][j][r] + bv;
    }
  }
}

// ---------------- flash attention (transposed: S^T = K Q^T, O^T = V^T P^T) ----
// Lane holds ONE q-row (q = l15); keys/dims spread over quads+regs.
// Softmax reductions: 15 in-lane ops + 2 shfl_xor (vs 32 shfls before).
// P transpose: 4 ds_write_b64 + 2 ds_read_b128 (wave-private, no barrier).
#define LSTR 72
#define PSTR 72
__global__ __launch_bounds__(256, 2) void attn_kernel(
    const bf16* __restrict__ Qb, const bf16* __restrict__ Kb,
    const bf16* __restrict__ Vt, bf16* __restrict__ Ob)
{
  __shared__ bf16 lK[64 * LSTR];
  __shared__ bf16 lV[64 * LSTR];
  __shared__ bf16 lP[4][16 * PSTR];

  const int tid = threadIdx.x;
  const int wave = tid >> 6, lane = tid & 63;
  const int l15 = lane & 15, quad = lane >> 4;
  const int qt = blockIdx.x & 31;
  const int bh = blockIdx.x >> 5;

  // Q fragment (B-operand: n=q=l15, k=quad*8+j) — same layout as A-operand
  const int qrow = qt * 64 + wave * 16 + l15;
  const bf16* qptr = Qb + ((size_t)bh * SEQ + qrow) * HDIM + quad * 8;
  bf16x8 qf0 = *(const bf16x8*)qptr;
  bf16x8 qf1 = *(const bf16x8*)(qptr + 32);

  f32x4 oacc[4] = {};          // oacc[fd][r] = O[q=l15][d=fd*16+quad*4+r]
  float mrow = -1e30f, lrow = 0.f;

  for (int kt = 0; kt < SEQ / 64; kt++) {
    __syncthreads();
#pragma unroll
    for (int it = 0; it < 2; it++) {
      const int idx = tid + it * 256;
      const int row = idx >> 3, ch = (idx & 7) * 8;
      *(uint4*)&lK[row * LSTR + ch] =
          *(const uint4*)&Kb[((size_t)bh * SEQ + kt * 64 + row) * HDIM + ch];
      *(uint4*)&lV[row * LSTR + ch] =
          *(const uint4*)&Vt[((size_t)bh * HDIM + row) * SEQ + kt * 64 + ch];
    }
    __syncthreads();

    // S^T tiles: sacc[fn][r] = S[q=l15][key = fn*16 + quad*4 + r]
    f32x4 sacc[4];
#pragma unroll
    for (int fn = 0; fn < 4; fn++) {
      f32x4 a = {};
      bf16x8 kf0 = *(const bf16x8*)&lK[(fn * 16 + l15) * LSTR + quad * 8];
      bf16x8 kf1 = *(const bf16x8*)&lK[(fn * 16 + l15) * LSTR + 32 + quad * 8];
      a = __builtin_amdgcn_mfma_f32_16x16x32_bf16(kf0, qf0, a, 0, 0, 0);
      a = __builtin_amdgcn_mfma_f32_16x16x32_bf16(kf1, qf1, a, 0, 0, 0);
      sacc[fn] = a;
    }

    // row max: 16 in-lane values, then 2 shfl_xor across quads
    float mx = -1e30f;
#pragma unroll
    for (int fn = 0; fn < 4; fn++)
#pragma unroll
      for (int r = 0; r < 4; r++) mx = fmaxf(mx, sacc[fn][r]);
    mx = fmaxf(mx, __shfl_xor(mx, 16, 64));
    mx = fmaxf(mx, __shfl_xor(mx, 32, 64));
    const float nm = fmaxf(mrow, mx);
    const float alpha = __expf(mrow - nm);
    mrow = nm;

    // exp + row sum
    float rs = 0.f;
#pragma unroll
    for (int fn = 0; fn < 4; fn++)
#pragma unroll
      for (int r = 0; r < 4; r++) {
        const float p = __expf(sacc[fn][r] - nm);
        sacc[fn][r] = p;
        rs += p;
      }
    rs += __shfl_xor(rs, 16, 64);
    rs += __shfl_xor(rs, 32, 64);
    lrow = lrow * alpha + rs;
#pragma unroll
    for (int fd = 0; fd < 4; fd++)
#pragma unroll
      for (int r = 0; r < 4; r++) oacc[fd][r] *= alpha;

    // P -> B-operand layout via wave-private LDS (4 consecutive keys per lane)
#pragma unroll
    for (int fn = 0; fn < 4; fn++) {
      bf16x4 pk = { (bf16)sacc[fn][0], (bf16)sacc[fn][1],
                    (bf16)sacc[fn][2], (bf16)sacc[fn][3] };
      *(bf16x4*)&lP[wave][l15 * PSTR + fn * 16 + quad * 4] = pk;
    }
    bf16x8 pf0 = *(const bf16x8*)&lP[wave][l15 * PSTR + quad * 8];
    bf16x8 pf1 = *(const bf16x8*)&lP[wave][l15 * PSTR + 32 + quad * 8];

    // O^T += V^T P^T
#pragma unroll
    for (int fd = 0; fd < 4; fd++) {
      bf16x8 vf0 = *(const bf16x8*)&lV[(fd * 16 + l15) * LSTR + quad * 8];
      bf16x8 vf1 = *(const bf16x8*)&lV[(fd * 16 + l15) * LSTR + 32 + quad * 8];
      oacc[fd] = __builtin_amdgcn_mfma_f32_16x16x32_bf16(vf0, pf0, oacc[fd], 0, 0, 0);
      oacc[fd] = __builtin_amdgcn_mfma_f32_16x16x32_bf16(vf1, pf1, oacc[fd], 0, 0, 0);
    }
  }

  // epilogue: lane writes 4 consecutive d per fd tile (b64 stores)
  const int b = bh >> 4, h = bh & 15;
  const float inv = 1.f / lrow;
  const int s = qt * 64 + wave * 16 + l15;
#pragma unroll
  for (int fd = 0; fd < 4; fd++) {
    bf16x4 ov = { (bf16)(oacc[fd][0] * inv), (bf16)(oacc[fd][1] * inv),
                  (bf16)(oacc[fd][2] * inv), (bf16)(oacc[fd][3] * inv) };
    *(bf16x4*)&Ob[((size_t)b * SEQ + s) * DIMD + h * HDIM + fd * 16 + quad * 4] = ov;
  }
}

extern "C" void kernel_launch(void* const* d_in, const int* in_sizes, int n_in,
                              void* d_out, int out_size, void* d_ws, size_t ws_size,
                              hipStream_t stream) {
  const float* x      = (const float*)d_in[0];
  const float* w_qkv  = (const float*)d_in[1];
  const float* b_qkv  = (const float*)d_in[2];
  const float* w_proj = (const float*)d_in[3];
  const float* b_proj = (const float*)d_in[4];
  float* out = (float*)d_out;
  char* ws = (char*)d_ws;

  bf16* Qb = (bf16*)d_out;
  bf16* Kb = (bf16*)d_out + (size_t)MTOT * DIMD;
  bf16* Vt     = (bf16*)(ws + OFF_VT);
  bf16* wqkvb  = (bf16*)(ws + OFF_WQKV);
  bf16* Ob     = (bf16*)(ws + OFF_OB);
  bf16* wprojb = (bf16*)(ws + OFF_WPROJ);

  cvt_kernel<<<(3 * DIMD * DIMD / 4) / 256, 256, 0, stream>>>(w_qkv, wqkvb, 3 * DIMD * DIMD / 4);
  gemm_qkv<<<dim3(24, 32), 256, 0, stream>>>(x, wqkvb, b_qkv, Qb, Kb, Vt);
  attn_kernel<<<BATCH * NHEAD * (SEQ / 64), 256, 0, stream>>>(Qb, Kb, Vt, Ob);
  cvt_kernel<<<(DIMD * DIMD / 4) / 256, 256, 0, stream>>>(w_proj, wprojb, DIMD * DIMD / 4);
  gemm_proj<<<dim3(8, 64), 256, 0, stream>>>(Ob, wprojb, b_proj, out);
}

// Round 4
// 222.546 us; speedup vs baseline: 1.2556x; 1.0749x over previous
//
#include <hip/hip_runtime.h>

typedef __bf16 bf16;
typedef __bf16 bf16x4 __attribute__((ext_vector_type(4)));
typedef __bf16 bf16x8 __attribute__((ext_vector_type(8)));
typedef float f32x4 __attribute__((ext_vector_type(4)));
typedef float f32x16 __attribute__((ext_vector_type(16)));

#define DIMD 1024
#define NHEAD 16
#define HDIM 64
#define BATCH 2
#define SEQ 2048
#define MTOT (BATCH*SEQ)   // 4096

// ---- memory plan (total ws use = 16 MB) ----
// d_out: [0,8MB) Qb bf16 [32][2048][64] (pre-scaled 1/8); [8,16MB) Kb
// d_ws:  [0,8MB) Vt bf16 [32][64][2048] -> dead after attn, wprojb at [0,2MB)
//        [8,14MB) wqkvb -> dead after QKV GEMM; [8,16MB) Ob bf16 [4096][1024]
#define OFF_VT    (0ull)
#define OFF_WQKV  (8ull<<20)
#define OFF_OB    (8ull<<20)
#define OFF_WPROJ (0ull)

__device__ __forceinline__ void g2l16(const void* g, void* l) {
  __builtin_amdgcn_global_load_lds(
      (const __attribute__((address_space(1))) void*)g,
      (__attribute__((address_space(3))) void*)l,
      16, 0, 0);
}

// ---------------- fp32 -> bf16 conversion ----------------
__global__ __launch_bounds__(256) void cvt_kernel(const float* __restrict__ in,
                                                  bf16* __restrict__ out, int n4) {
  int i = blockIdx.x * blockDim.x + threadIdx.x;
  if (i < n4) {
    float4 v = ((const float4*)in)[i];
    bf16x4 o = { (bf16)v.x, (bf16)v.y, (bf16)v.z, (bf16)v.w };
    ((bf16x4*)out)[i] = o;
  }
}

// ---------------- QKV GEMM: C[m][n] = sum_k x[m][k]*Wt[n][k] + b ----------------
__global__ __launch_bounds__(256, 2) void gemm_qkv(
    const float* __restrict__ x, const bf16* __restrict__ Wt,
    const float* __restrict__ bias,
    bf16* __restrict__ Qb, bf16* __restrict__ Kb, bf16* __restrict__ Vt)
{
  __shared__ bf16 lA[128 * 32];
  __shared__ bf16 lB[128 * 32];
  const int tid = threadIdx.x;
  const int wave = tid >> 6, lane = tid & 63;
  const int l15 = lane & 15, quad = lane >> 4;
  const int wm = wave >> 1, wn = wave & 1;
  const int tm = blockIdx.y * 128, tn = blockIdx.x * 128;

  f32x4 acc[4][4] = {};

  const int arowA = tid >> 1;            // 0..127
  const int acolA = (tid & 1) * 16;      // 0 or 16
  const int brow = tid >> 2;             // 0..63
  const int bchunk = (tid & 3) * 8;

  for (int kb = 0; kb < DIMD; kb += 32) {
    const float* gx = &x[(size_t)(tm + arowA) * DIMD + kb + acolA];
    float4 v0 = ((const float4*)gx)[0];
    float4 v1 = ((const float4*)gx)[1];
    float4 v2 = ((const float4*)gx)[2];
    float4 v3 = ((const float4*)gx)[3];
    __syncthreads();
    const bf16* gB = &Wt[(size_t)(tn + brow) * DIMD + kb + bchunk];
    g2l16(gB,                     &lB[wave * 512]);
    g2l16(gB + (size_t)64 * DIMD, &lB[2048 + wave * 512]);
    bf16x8 a0 = { (bf16)v0.x, (bf16)v0.y, (bf16)v0.z, (bf16)v0.w,
                  (bf16)v1.x, (bf16)v1.y, (bf16)v1.z, (bf16)v1.w };
    bf16x8 a1 = { (bf16)v2.x, (bf16)v2.y, (bf16)v2.z, (bf16)v2.w,
                  (bf16)v3.x, (bf16)v3.y, (bf16)v3.z, (bf16)v3.w };
    *(bf16x8*)&lA[arowA * 32 + acolA]     = a0;
    *(bf16x8*)&lA[arowA * 32 + acolA + 8] = a1;
    __syncthreads();

    bf16x8 af[4], bfr[4];
#pragma unroll
    for (int i = 0; i < 4; i++)
      af[i] = *(const bf16x8*)&lA[(wm * 64 + i * 16 + l15) * 32 + quad * 8];
#pragma unroll
    for (int i = 0; i < 4; i++)
      bfr[i] = *(const bf16x8*)&lB[(wn * 64 + i * 16 + l15) * 32 + quad * 8];
#pragma unroll
    for (int i = 0; i < 4; i++)
#pragma unroll
      for (int j = 0; j < 4; j++)
        acc[i][j] = __builtin_amdgcn_mfma_f32_16x16x32_bf16(af[i], bfr[j], acc[i][j], 0, 0, 0);
  }

  const int sel = tn >> 10;  // 0=Q 1=K 2=V
#pragma unroll
  for (int j = 0; j < 4; j++) {
    const int n = tn + wn * 64 + j * 16 + l15;
    const float bv = bias[n];
    const int d = n & 1023, h = d >> 6, hd = d & 63;
#pragma unroll
    for (int i = 0; i < 4; i++) {
      const int mbase = tm + wm * 64 + i * 16 + quad * 4;
#pragma unroll
      for (int r = 0; r < 4; r++) {
        const int mm = mbase + r;
        const int b = mm >> 11, s = mm & 2047;
        const int bh = b * NHEAD + h;
        float v = acc[i][j][r] + bv;
        if (sel == 0)      Qb[((size_t)bh * SEQ + s) * HDIM + hd] = (bf16)(v * 0.125f);
        else if (sel == 1) Kb[((size_t)bh * SEQ + s) * HDIM + hd] = (bf16)v;
        else               Vt[((size_t)bh * HDIM + hd) * SEQ + s] = (bf16)v;
      }
    }
  }
}

// ---------------- proj GEMM: 64x128 tile (512 blocks = 2/CU) ----------------
__global__ __launch_bounds__(256, 2) void gemm_proj(
    const bf16* __restrict__ A, const bf16* __restrict__ Bt,
    const float* __restrict__ bias, float* __restrict__ out)
{
  __shared__ bf16 lA[64 * 32];
  __shared__ bf16 lB[128 * 32];
  const int tid = threadIdx.x;
  const int wave = tid >> 6, lane = tid & 63;
  const int l15 = lane & 15, quad = lane >> 4;
  const int tm = blockIdx.y * 64, tn = blockIdx.x * 128;

  f32x4 acc[4][2] = {};
  const int row = tid >> 2;          // 0..63
  const int ch = (tid & 3) * 8;

  for (int kb = 0; kb < DIMD; kb += 32) {
    __syncthreads();
    g2l16(&A[(size_t)(tm + row) * DIMD + kb + ch],        &lA[wave * 512]);
    g2l16(&Bt[(size_t)(tn + row) * DIMD + kb + ch],       &lB[wave * 512]);
    g2l16(&Bt[(size_t)(tn + 64 + row) * DIMD + kb + ch],  &lB[2048 + wave * 512]);
    __syncthreads();

    bf16x8 af[4], bfr[2];
#pragma unroll
    for (int i = 0; i < 4; i++)
      af[i] = *(const bf16x8*)&lA[(i * 16 + l15) * 32 + quad * 8];
#pragma unroll
    for (int j = 0; j < 2; j++)
      bfr[j] = *(const bf16x8*)&lB[(wave * 32 + j * 16 + l15) * 32 + quad * 8];
#pragma unroll
    for (int i = 0; i < 4; i++)
#pragma unroll
      for (int j = 0; j < 2; j++)
        acc[i][j] = __builtin_amdgcn_mfma_f32_16x16x32_bf16(af[i], bfr[j], acc[i][j], 0, 0, 0);
  }

#pragma unroll
  for (int j = 0; j < 2; j++) {
    const int n = tn + wave * 32 + j * 16 + l15;
    const float bv = bias[n];
#pragma unroll
    for (int i = 0; i < 4; i++) {
      const int mbase = tm + i * 16 + quad * 4;
#pragma unroll
      for (int r = 0; r < 4; r++)
        out[(size_t)(mbase + r) * DIMD + n] = acc[i][j][r] + bv;
    }
  }
}

// ---------------- flash attention v3: 32x32x16 MFMA, 128 q/block ----------------
// grid: 32 bh * 16 qt = 512 blocks; 4 waves, wave owns 32 q rows (q = lane&31).
// Lane (q, h=lane>>5) holds half the keys; lane^32 the other half -> 1 shfl_xor
// per reduction. LDS/FLOP halved vs 16x16 shape. All strides 72 (16B-aligned,
// conflict-optimal phases for b128/b64/uint4 access).
#define LSTR 72
__global__ __launch_bounds__(256, 2) void attn_kernel(
    const bf16* __restrict__ Qb, const bf16* __restrict__ Kb,
    const bf16* __restrict__ Vt, bf16* __restrict__ Ob)
{
  __shared__ bf16 lK[64 * LSTR];
  __shared__ bf16 lV[64 * LSTR];
  __shared__ bf16 lP[4][32 * LSTR];

  const int tid = threadIdx.x;
  const int wave = tid >> 6, lane = tid & 63;
  const int l31 = lane & 31, h = lane >> 5;
  const int qt = blockIdx.x & 15;
  const int bh = blockIdx.x >> 4;

  // Q B-operand frags: Q[q=l31][k = c*16 + h*8 + j], held whole kernel
  const int qrow = qt * 128 + wave * 32 + l31;
  const bf16* qp = Qb + ((size_t)bh * SEQ + qrow) * HDIM + h * 8;
  bf16x8 qf[4];
#pragma unroll
  for (int c = 0; c < 4; c++) qf[c] = *(const bf16x8*)(qp + c * 16);

  f32x16 o0 = {}, o1 = {};   // O^T C-tiles: d 0-31 / 32-63, col q = l31
  float mrow = -1e30f, lrow = 0.f;

  for (int kt = 0; kt < SEQ / 64; kt++) {
    __syncthreads();
#pragma unroll
    for (int it = 0; it < 2; it++) {
      const int idx = tid + it * 256;
      const int row = idx >> 3, ch = (idx & 7) * 8;
      *(uint4*)&lK[row * LSTR + ch] =
          *(const uint4*)&Kb[((size_t)bh * SEQ + kt * 64 + row) * HDIM + ch];
      *(uint4*)&lV[row * LSTR + ch] =
          *(const uint4*)&Vt[((size_t)bh * HDIM + row) * SEQ + kt * 64 + ch];
    }
    __syncthreads();

    // S^T = K Q^T : two 32x32 tiles (keys 0-31, 32-63), col = q
    f32x16 s0 = {}, s1 = {};
#pragma unroll
    for (int c = 0; c < 4; c++) {
      bf16x8 k0 = *(const bf16x8*)&lK[l31 * LSTR + c * 16 + h * 8];
      bf16x8 k1 = *(const bf16x8*)&lK[(32 + l31) * LSTR + c * 16 + h * 8];
      s0 = __builtin_amdgcn_mfma_f32_32x32x16_bf16(k0, qf[c], s0, 0, 0, 0);
      s1 = __builtin_amdgcn_mfma_f32_32x32x16_bf16(k1, qf[c], s1, 0, 0, 0);
    }

    // online softmax: 32 in-lane values + 1 shfl_xor(32) (lane^32 = same q)
    float mx = -1e30f;
#pragma unroll
    for (int r = 0; r < 16; r++) { mx = fmaxf(mx, s0[r]); mx = fmaxf(mx, s1[r]); }
    mx = fmaxf(mx, __shfl_xor(mx, 32, 64));
    const float nm = fmaxf(mrow, mx);
    const float alpha = __expf(mrow - nm);
    mrow = nm;

    float rs = 0.f;
#pragma unroll
    for (int r = 0; r < 16; r++) {
      const float p0 = __expf(s0[r] - nm);
      const float p1 = __expf(s1[r] - nm);
      s0[r] = p0; s1[r] = p1;
      rs += p0 + p1;
    }
    rs += __shfl_xor(rs, 32, 64);
    lrow = lrow * alpha + rs;
#pragma unroll
    for (int r = 0; r < 16; r++) { o0[r] *= alpha; o1[r] *= alpha; }

    // P^T -> B-operand via wave-private LDS: lP[q][key]
    // C reg 4g+r holds key = 8g + 4h + r (+32 for tile 1)
#pragma unroll
    for (int g = 0; g < 4; g++) {
      bf16x4 pa = { (bf16)s0[4*g], (bf16)s0[4*g+1], (bf16)s0[4*g+2], (bf16)s0[4*g+3] };
      bf16x4 pb = { (bf16)s1[4*g], (bf16)s1[4*g+1], (bf16)s1[4*g+2], (bf16)s1[4*g+3] };
      *(bf16x4*)&lP[wave][l31 * LSTR + g * 8 + h * 4]      = pa;
      *(bf16x4*)&lP[wave][l31 * LSTR + 32 + g * 8 + h * 4] = pb;
    }
    bf16x8 pf[4];
#pragma unroll
    for (int c = 0; c < 4; c++)
      pf[c] = *(const bf16x8*)&lP[wave][l31 * LSTR + c * 16 + h * 8];

    // O^T += V^T P^T : two d-tiles
#pragma unroll
    for (int c = 0; c < 4; c++) {
      bf16x8 v0 = *(const bf16x8*)&lV[l31 * LSTR + c * 16 + h * 8];
      bf16x8 v1 = *(const bf16x8*)&lV[(32 + l31) * LSTR + c * 16 + h * 8];
      o0 = __builtin_amdgcn_mfma_f32_32x32x16_bf16(v0, pf[c], o0, 0, 0, 0);
      o1 = __builtin_amdgcn_mfma_f32_32x32x16_bf16(v1, pf[c], o1, 0, 0, 0);
    }
  }

  // epilogue: d = 8g + 4h + r (+32 for o1); s = qrow; b64 stores
  const int b = bh >> 4, head = bh & 15;
  const float inv = 1.f / lrow;
  const size_t base = ((size_t)b * SEQ + qrow) * DIMD + head * HDIM;
#pragma unroll
  for (int g = 0; g < 4; g++) {
    bf16x4 oa = { (bf16)(o0[4*g] * inv), (bf16)(o0[4*g+1] * inv),
                  (bf16)(o0[4*g+2] * inv), (bf16)(o0[4*g+3] * inv) };
    bf16x4 ob = { (bf16)(o1[4*g] * inv), (bf16)(o1[4*g+1] * inv),
                  (bf16)(o1[4*g+2] * inv), (bf16)(o1[4*g+3] * inv) };
    *(bf16x4*)&Ob[base + g * 8 + h * 4]      = oa;
    *(bf16x4*)&Ob[base + 32 + g * 8 + h * 4] = ob;
  }
}

extern "C" void kernel_launch(void* const* d_in, const int* in_sizes, int n_in,
                              void* d_out, int out_size, void* d_ws, size_t ws_size,
                              hipStream_t stream) {
  const float* x      = (const float*)d_in[0];
  const float* w_qkv  = (const float*)d_in[1];
  const float* b_qkv  = (const float*)d_in[2];
  const float* w_proj = (const float*)d_in[3];
  const float* b_proj = (const float*)d_in[4];
  float* out = (float*)d_out;
  char* ws = (char*)d_ws;

  bf16* Qb = (bf16*)d_out;
  bf16* Kb = (bf16*)d_out + (size_t)MTOT * DIMD;
  bf16* Vt     = (bf16*)(ws + OFF_VT);
  bf16* wqkvb  = (bf16*)(ws + OFF_WQKV);
  bf16* Ob     = (bf16*)(ws + OFF_OB);
  bf16* wprojb = (bf16*)(ws + OFF_WPROJ);

  cvt_kernel<<<(3 * DIMD * DIMD / 4) / 256, 256, 0, stream>>>(w_qkv, wqkvb, 3 * DIMD * DIMD / 4);
  gemm_qkv<<<dim3(24, 32), 256, 0, stream>>>(x, wqkvb, b_qkv, Qb, Kb, Vt);
  attn_kernel<<<BATCH * NHEAD * (SEQ / 128), 256, 0, stream>>>(Qb, Kb, Vt, Ob);
  cvt_kernel<<<(DIMD * DIMD / 4) / 256, 256, 0, stream>>>(w_proj, wprojb, DIMD * DIMD / 4);
  gemm_proj<<<dim3(8, 64), 256, 0, stream>>>(Ob, wprojb, b_proj, out);
}

// Round 6
// 204.852 us; speedup vs baseline: 1.3640x; 1.0864x over previous
//
#include <hip/hip_runtime.h>

typedef __bf16 bf16;
typedef __bf16 bf16x4 __attribute__((ext_vector_type(4)));
typedef __bf16 bf16x8 __attribute__((ext_vector_type(8)));
typedef float f32x4 __attribute__((ext_vector_type(4)));
typedef float f32x16 __attribute__((ext_vector_type(16)));

#define DIMD 1024
#define NHEAD 16
#define HDIM 64
#define BATCH 2
#define SEQ 2048
#define MTOT (BATCH*SEQ)   // 4096

#define EXP2F(x) __builtin_amdgcn_exp2f(x)

// ---- memory plan (total ws use = 16 MB) ----
// d_out: [0,8MB) Qb bf16 [32][2048][64] (pre-scaled 0.125*log2e); [8,16MB) Kb
// d_ws:  [0,8MB) Vt bf16 [32][64][2048] -> dead after attn, wprojb at [0,2MB)
//        [8,14MB) wqkvb -> dead after QKV GEMM; [8,16MB) Ob bf16 [4096][1024]
#define OFF_VT    (0ull)
#define OFF_WQKV  (8ull<<20)
#define OFF_OB    (8ull<<20)
#define OFF_WPROJ (0ull)

__device__ __forceinline__ void g2l16(const void* g, void* l) {
  __builtin_amdgcn_global_load_lds(
      (const __attribute__((address_space(1))) void*)g,
      (__attribute__((address_space(3))) void*)l,
      16, 0, 0);
}

// ---------------- fp32 -> bf16 conversion ----------------
__global__ __launch_bounds__(256) void cvt_kernel(const float* __restrict__ in,
                                                  bf16* __restrict__ out, int n4) {
  int i = blockIdx.x * blockDim.x + threadIdx.x;
  if (i < n4) {
    float4 v = ((const float4*)in)[i];
    bf16x4 o = { (bf16)v.x, (bf16)v.y, (bf16)v.z, (bf16)v.w };
    ((bf16x4*)out)[i] = o;
  }
}

// ---------------- QKV GEMM: C[m][n] = sum_k x[m][k]*Wt[n][k] + b ----------------
__global__ __launch_bounds__(256, 2) void gemm_qkv(
    const float* __restrict__ x, const bf16* __restrict__ Wt,
    const float* __restrict__ bias,
    bf16* __restrict__ Qb, bf16* __restrict__ Kb, bf16* __restrict__ Vt)
{
  __shared__ bf16 lA[128 * 32];
  __shared__ bf16 lB[128 * 32];
  const int tid = threadIdx.x;
  const int wave = tid >> 6, lane = tid & 63;
  const int l15 = lane & 15, quad = lane >> 4;
  const int wm = wave >> 1, wn = wave & 1;
  const int tm = blockIdx.y * 128, tn = blockIdx.x * 128;

  f32x4 acc[4][4] = {};

  const int arowA = tid >> 1;            // 0..127
  const int acolA = (tid & 1) * 16;      // 0 or 16
  const int brow = tid >> 2;             // 0..63
  const int bchunk = (tid & 3) * 8;

  for (int kb = 0; kb < DIMD; kb += 32) {
    const float* gx = &x[(size_t)(tm + arowA) * DIMD + kb + acolA];
    float4 v0 = ((const float4*)gx)[0];
    float4 v1 = ((const float4*)gx)[1];
    float4 v2 = ((const float4*)gx)[2];
    float4 v3 = ((const float4*)gx)[3];
    __syncthreads();
    const bf16* gB = &Wt[(size_t)(tn + brow) * DIMD + kb + bchunk];
    g2l16(gB,                     &lB[wave * 512]);
    g2l16(gB + (size_t)64 * DIMD, &lB[2048 + wave * 512]);
    bf16x8 a0 = { (bf16)v0.x, (bf16)v0.y, (bf16)v0.z, (bf16)v0.w,
                  (bf16)v1.x, (bf16)v1.y, (bf16)v1.z, (bf16)v1.w };
    bf16x8 a1 = { (bf16)v2.x, (bf16)v2.y, (bf16)v2.z, (bf16)v2.w,
                  (bf16)v3.x, (bf16)v3.y, (bf16)v3.z, (bf16)v3.w };
    *(bf16x8*)&lA[arowA * 32 + acolA]     = a0;
    *(bf16x8*)&lA[arowA * 32 + acolA + 8] = a1;
    __syncthreads();

    bf16x8 af[4], bfr[4];
#pragma unroll
    for (int i = 0; i < 4; i++)
      af[i] = *(const bf16x8*)&lA[(wm * 64 + i * 16 + l15) * 32 + quad * 8];
#pragma unroll
    for (int i = 0; i < 4; i++)
      bfr[i] = *(const bf16x8*)&lB[(wn * 64 + i * 16 + l15) * 32 + quad * 8];
#pragma unroll
    for (int i = 0; i < 4; i++)
#pragma unroll
      for (int j = 0; j < 4; j++)
        acc[i][j] = __builtin_amdgcn_mfma_f32_16x16x32_bf16(af[i], bfr[j], acc[i][j], 0, 0, 0);
  }

  const int sel = tn >> 10;  // 0=Q 1=K 2=V
#pragma unroll
  for (int j = 0; j < 4; j++) {
    const int n = tn + wn * 64 + j * 16 + l15;
    const float bv = bias[n];
    const int d = n & 1023, h = d >> 6, hd = d & 63;
#pragma unroll
    for (int i = 0; i < 4; i++) {
      const int mbase = tm + wm * 64 + i * 16 + quad * 4;
      const int b = mbase >> 11, s0 = mbase & 2047;
      const int bh = b * NHEAD + h;
      if (sel == 2) {
        // Vt[bh][hd][s]: 4 consecutive s -> vector store
        bf16x4 vv = { (bf16)(acc[i][j][0] + bv), (bf16)(acc[i][j][1] + bv),
                      (bf16)(acc[i][j][2] + bv), (bf16)(acc[i][j][3] + bv) };
        *(bf16x4*)&Vt[((size_t)bh * HDIM + hd) * SEQ + s0] = vv;
      } else {
#pragma unroll
        for (int r = 0; r < 4; r++) {
          float v = acc[i][j][r] + bv;
          if (sel == 0)
            Qb[((size_t)bh * SEQ + s0 + r) * HDIM + hd] = (bf16)(v * 0.18033688f); // 0.125*log2e
          else
            Kb[((size_t)bh * SEQ + s0 + r) * HDIM + hd] = (bf16)v;
        }
      }
    }
  }
}

// ---------------- proj GEMM: 64x128 tile (512 blocks = 2/CU) ----------------
__global__ __launch_bounds__(256, 2) void gemm_proj(
    const bf16* __restrict__ A, const bf16* __restrict__ Bt,
    const float* __restrict__ bias, float* __restrict__ out)
{
  __shared__ bf16 lA[64 * 32];
  __shared__ bf16 lB[128 * 32];
  const int tid = threadIdx.x;
  const int wave = tid >> 6, lane = tid & 63;
  const int l15 = lane & 15, quad = lane >> 4;
  const int tm = blockIdx.y * 64, tn = blockIdx.x * 128;

  f32x4 acc[4][2] = {};
  const int row = tid >> 2;          // 0..63
  const int ch = (tid & 3) * 8;

  for (int kb = 0; kb < DIMD; kb += 32) {
    __syncthreads();
    g2l16(&A[(size_t)(tm + row) * DIMD + kb + ch],        &lA[wave * 512]);
    g2l16(&Bt[(size_t)(tn + row) * DIMD + kb + ch],       &lB[wave * 512]);
    g2l16(&Bt[(size_t)(tn + 64 + row) * DIMD + kb + ch],  &lB[2048 + wave * 512]);
    __syncthreads();

    bf16x8 af[4], bfr[2];
#pragma unroll
    for (int i = 0; i < 4; i++)
      af[i] = *(const bf16x8*)&lA[(i * 16 + l15) * 32 + quad * 8];
#pragma unroll
    for (int j = 0; j < 2; j++)
      bfr[j] = *(const bf16x8*)&lB[(wave * 32 + j * 16 + l15) * 32 + quad * 8];
#pragma unroll
    for (int i = 0; i < 4; i++)
#pragma unroll
      for (int j = 0; j < 2; j++)
        acc[i][j] = __builtin_amdgcn_mfma_f32_16x16x32_bf16(af[i], bfr[j], acc[i][j], 0, 0, 0);
  }

#pragma unroll
  for (int j = 0; j < 2; j++) {
    const int n = tn + wave * 32 + j * 16 + l15;
    const float bv = bias[n];
#pragma unroll
    for (int i = 0; i < 4; i++) {
      const int mbase = tm + i * 16 + quad * 4;
#pragma unroll
      for (int r = 0; r < 4; r++)
        out[(size_t)(mbase + r) * DIMD + n] = acc[i][j][r] + bv;
    }
  }
}

// ---------------- flash attention v5 ----------------
// 32x32x16 MFMA, 128 q/block, 512 blocks, XCD-swizzled.
// Double-buffered LDS K/V + register prefetch: ONE barrier per iter; the
// global loads for tile kt+1 are issued right after the barrier and consumed
// by the ds_write at the top of the next iter (latency hidden under compute).
// Softmax in log2 domain (Q pre-scaled by 0.125*log2e) -> bare v_exp_f32.
#define LSTR 72
__global__ __launch_bounds__(256, 2) void attn_kernel(
    const bf16* __restrict__ Qb, const bf16* __restrict__ Kb,
    const bf16* __restrict__ Vt, bf16* __restrict__ Ob)
{
  __shared__ bf16 lKV[2][2][64 * LSTR];   // [buf][K=0/V=1][row*LSTR+col]
  __shared__ bf16 lP[4][32 * LSTR];

  const int tid = threadIdx.x;
  const int wave = tid >> 6, lane = tid & 63;
  const int l31 = lane & 31, h = lane >> 5;
  // XCD swizzle: all 16 q-tiles of a head land on one XCD (4 heads/XCD in L2)
  const int xcd = blockIdx.x & 7, grp = blockIdx.x >> 3;
  const int bh = xcd + 8 * (grp & 3);
  const int qt = grp >> 2;

  // Q B-operand frags (pre-scaled to log2 domain by gemm_qkv)
  const int qrow = qt * 128 + wave * 32 + l31;
  const bf16* qp = Qb + ((size_t)bh * SEQ + qrow) * HDIM + h * 8;
  bf16x8 qf[4];
#pragma unroll
  for (int c = 0; c < 4; c++) qf[c] = *(const bf16x8*)(qp + c * 16);

  // staging addresses: 256 threads cover rows 0..31 per inst, 2 insts each
  const int srow = tid >> 3;            // 0..31
  const int sch = (tid & 7) * 8;        // bf16 elem offset in 64
  const bf16* kg = Kb + ((size_t)bh * SEQ + srow) * HDIM + sch;
  const bf16* vg = Vt + ((size_t)bh * HDIM + srow) * SEQ + sch;

  // preload tile 0 into regs
  uint4 kr0 = *(const uint4*)(kg);
  uint4 kr1 = *(const uint4*)(kg + 32 * HDIM);
  uint4 vr0 = *(const uint4*)(vg);
  uint4 vr1 = *(const uint4*)(vg + 32 * SEQ);

  f32x16 o0 = {}, o1 = {};
  float mrow = -1e30f, lrow = 0.f;

  for (int kt = 0; kt < SEQ / 64; kt++) {
    bf16* sK = lKV[kt & 1][0];
    bf16* sV = lKV[kt & 1][1];
    *(uint4*)&sK[srow * LSTR + sch]        = kr0;
    *(uint4*)&sK[(32 + srow) * LSTR + sch] = kr1;
    *(uint4*)&sV[srow * LSTR + sch]        = vr0;
    *(uint4*)&sV[(32 + srow) * LSTR + sch] = vr1;
    __syncthreads();

    // prefetch tile kt+1 (wraps to 0 on last iter; harmless)
    const int ktn = (kt + 1) & (SEQ / 64 - 1);
    kr0 = *(const uint4*)(kg + (size_t)ktn * 64 * HDIM);
    kr1 = *(const uint4*)(kg + (size_t)ktn * 64 * HDIM + 32 * HDIM);
    vr0 = *(const uint4*)(vg + ktn * 64);
    vr1 = *(const uint4*)(vg + ktn * 64 + 32 * SEQ);

    // S^T = K Q^T : two 32x32 tiles (keys 0-31, 32-63), col = q = l31
    f32x16 s0 = {}, s1 = {};
#pragma unroll
    for (int c = 0; c < 4; c++) {
      bf16x8 k0 = *(const bf16x8*)&sK[l31 * LSTR + c * 16 + h * 8];
      bf16x8 k1 = *(const bf16x8*)&sK[(32 + l31) * LSTR + c * 16 + h * 8];
      s0 = __builtin_amdgcn_mfma_f32_32x32x16_bf16(k0, qf[c], s0, 0, 0, 0);
      s1 = __builtin_amdgcn_mfma_f32_32x32x16_bf16(k1, qf[c], s1, 0, 0, 0);
    }

    // online softmax, log2 domain: 32 in-lane + 1 shfl_xor(32)
    float mx = -1e30f;
#pragma unroll
    for (int r = 0; r < 16; r++) { mx = fmaxf(mx, s0[r]); mx = fmaxf(mx, s1[r]); }
    mx = fmaxf(mx, __shfl_xor(mx, 32, 64));
    const float nm = fmaxf(mrow, mx);
    const float alpha = EXP2F(mrow - nm);
    mrow = nm;

    float rs = 0.f;
#pragma unroll
    for (int r = 0; r < 16; r++) {
      const float p0 = EXP2F(s0[r] - nm);
      const float p1 = EXP2F(s1[r] - nm);
      s0[r] = p0; s1[r] = p1;
      rs += p0 + p1;
    }
    rs += __shfl_xor(rs, 32, 64);
    lrow = lrow * alpha + rs;
#pragma unroll
    for (int r = 0; r < 16; r++) { o0[r] *= alpha; o1[r] *= alpha; }

    // P^T -> B-operand via wave-private LDS (DS ops are wave-ordered: safe)
#pragma unroll
    for (int g = 0; g < 4; g++) {
      bf16x4 pa = { (bf16)s0[4*g], (bf16)s0[4*g+1], (bf16)s0[4*g+2], (bf16)s0[4*g+3] };
      bf16x4 pb = { (bf16)s1[4*g], (bf16)s1[4*g+1], (bf16)s1[4*g+2], (bf16)s1[4*g+3] };
      *(bf16x4*)&lP[wave][l31 * LSTR + g * 8 + h * 4]      = pa;
      *(bf16x4*)&lP[wave][l31 * LSTR + 32 + g * 8 + h * 4] = pb;
    }
    bf16x8 pf[4];
#pragma unroll
    for (int c = 0; c < 4; c++)
      pf[c] = *(const bf16x8*)&lP[wave][l31 * LSTR + c * 16 + h * 8];

    // O^T += V^T P^T
#pragma unroll
    for (int c = 0; c < 4; c++) {
      bf16x8 v0 = *(const bf16x8*)&sV[l31 * LSTR + c * 16 + h * 8];
      bf16x8 v1 = *(const bf16x8*)&sV[(32 + l31) * LSTR + c * 16 + h * 8];
      o0 = __builtin_amdgcn_mfma_f32_32x32x16_bf16(v0, pf[c], o0, 0, 0, 0);
      o1 = __builtin_amdgcn_mfma_f32_32x32x16_bf16(v1, pf[c], o1, 0, 0, 0);
    }
  }

  // epilogue: d = 8g + 4h + r (+32 for o1); s = qrow; b64 stores
  const int b = bh >> 4, head = bh & 15;
  const float inv = 1.f / lrow;
  const size_t base = ((size_t)b * SEQ + qrow) * DIMD + head * HDIM;
#pragma unroll
  for (int g = 0; g < 4; g++) {
    bf16x4 oa = { (bf16)(o0[4*g] * inv), (bf16)(o0[4*g+1] * inv),
                  (bf16)(o0[4*g+2] * inv), (bf16)(o0[4*g+3] * inv) };
    bf16x4 ob = { (bf16)(o1[4*g] * inv), (bf16)(o1[4*g+1] * inv),
                  (bf16)(o1[4*g+2] * inv), (bf16)(o1[4*g+3] * inv) };
    *(bf16x4*)&Ob[base + g * 8 + h * 4]      = oa;
    *(bf16x4*)&Ob[base + 32 + g * 8 + h * 4] = ob;
  }
}

extern "C" void kernel_launch(void* const* d_in, const int* in_sizes, int n_in,
                              void* d_out, int out_size, void* d_ws, size_t ws_size,
                              hipStream_t stream) {
  const float* x      = (const float*)d_in[0];
  const float* w_qkv  = (const float*)d_in[1];
  const float* b_qkv  = (const float*)d_in[2];
  const float* w_proj = (const float*)d_in[3];
  const float* b_proj = (const float*)d_in[4];
  float* out = (float*)d_out;
  char* ws = (char*)d_ws;

  bf16* Qb = (bf16*)d_out;
  bf16* Kb = (bf16*)d_out + (size_t)MTOT * DIMD;
  bf16* Vt     = (bf16*)(ws + OFF_VT);
  bf16* wqkvb  = (bf16*)(ws + OFF_WQKV);
  bf16* Ob     = (bf16*)(ws + OFF_OB);
  bf16* wprojb = (bf16*)(ws + OFF_WPROJ);

  cvt_kernel<<<(3 * DIMD * DIMD / 4) / 256, 256, 0, stream>>>(w_qkv, wqkvb, 3 * DIMD * DIMD / 4);
  gemm_qkv<<<dim3(24, 32), 256, 0, stream>>>(x, wqkvb, b_qkv, Qb, Kb, Vt);
  attn_kernel<<<BATCH * NHEAD * (SEQ / 128), 256, 0, stream>>>(Qb, Kb, Vt, Ob);
  cvt_kernel<<<(DIMD * DIMD / 4) / 256, 256, 0, stream>>>(w_proj, wprojb, DIMD * DIMD / 4);
  gemm_proj<<<dim3(8, 64), 256, 0, stream>>>(Ob, wprojb, b_proj, out);
}